// Round 3
// baseline (458.515 us; speedup 1.0000x reference)
//
#include <hip/hip_runtime.h>
#include <hip/hip_bf16.h>
#include <hip/hip_fp8.h>
#include <cstdint>
#include <cstddef>

// Problem: B=4, S=4096, D=256 two-layer full attention + VAE head. fp32 I/O.
// Strategy: MX-scaled fp8 MFMA flash attention with counted-vmcnt pipeline
// (no vmcnt(0) drains in main loop); bf16 MFMA GEMMs; fp32 softmax/epilogue.

#define S_LEN 4096
#define DMODEL 256
#define NBATCH 4

typedef __bf16 bf16;
typedef __bf16 bf16x8 __attribute__((ext_vector_type(8)));
typedef float f32x4 __attribute__((ext_vector_type(4)));
typedef float f32x16 __attribute__((ext_vector_type(16)));
typedef int i32x4 __attribute__((ext_vector_type(4)));
typedef int i32x8 __attribute__((ext_vector_type(8)));
typedef unsigned char u8;
typedef unsigned int u32;

__device__ __forceinline__ f32x4 mfma16(bf16x8 a, bf16x8 b, f32x4 c) {
  return __builtin_amdgcn_mfma_f32_16x16x32_bf16(a, b, c, 0, 0, 0);
}
// MX-scaled fp8 MFMA, K=64, unit scales (e8m0 0x7F = 2^0): plain fp8 matmul at 2x rate.
__device__ __forceinline__ f32x16 mfma_mx(i32x8 a, i32x8 b, f32x16 c) {
  return __builtin_amdgcn_mfma_scale_f32_32x32x64_f8f6f4(
      a, b, c, 0, 0, 0, 0x7F7F7F7F, 0, 0x7F7F7F7F);
}
__device__ __forceinline__ i32x8 cat8(i32x4 a, i32x4 b) {
  return __builtin_shufflevector(a, b, 0, 1, 2, 3, 4, 5, 6, 7);
}

// Async global->LDS, 16B per lane. LDS dest: wave-uniform base + lane*16.
__device__ __forceinline__ void async16(const void* g, void* lds) {
  __builtin_amdgcn_global_load_lds(
      (const __attribute__((address_space(1))) unsigned int*)g,
      (__attribute__((address_space(3))) unsigned int*)lds, 16, 0, 0);
}

__device__ __forceinline__ unsigned short f2bfbits(float f) {
  return __builtin_bit_cast(unsigned short, (bf16)f);
}
__device__ __forceinline__ u8 f2fp8(float f) {
  __hip_fp8_e4m3 t(f);  // OCP e4m3fn
  return *(u8*)&t;
}
// half-split column permutation over 256-wide d for K=64 scaled MFMA:
// k = b2*64 + h*32 + m -> position h*128 + b2*32 + m.
__device__ __forceinline__ int permc(int v) {
  return (((v >> 5) & 1) << 7) + (((v >> 6) & 3) << 5) + (v & 31);
}

// ---------------- cast kernel (x + 8 weight mats in one launch) ----------------
struct WPtrs { const float* p[8]; };

__global__ void cast_all_kernel(const f32x4* __restrict__ x, WPtrs wp,
                                ushort4* __restrict__ x16, ushort4* __restrict__ w16) {
  int bx = blockIdx.x, t = threadIdx.x;
  const f32x4* src;
  ushort4* dst;
  if (bx < 4096) {
    src = x + (size_t)bx * 256 + t;
    dst = x16 + (size_t)bx * 256 + t;
  } else {
    int r = bx - 4096;
    int m = r >> 6;
    int i = (r & 63) * 256 + t;
    src = (const f32x4*)wp.p[m] + i;
    dst = w16 + (size_t)m * 16384 + i;
  }
  f32x4 v = *src;
  ushort4 o;
  o.x = f2bfbits(v[0]); o.y = f2bfbits(v[1]); o.z = f2bfbits(v[2]); o.w = f2bfbits(v[3]);
  *dst = o;
}

// ---------------- GEMM: out[m][n] = sum_k A[m][k]*W[n][k] + bias[n] ----------------
// z=0: Q fp8 (plain [M][256]); z=1: K fp8 (permc cols, [M][256]);
// z=2: V fp8 transposed tile-major [B][S/64][256 d][64 s].
struct GemmIO {
  const float* bias[3];
  void* out[3];
};

__global__ __launch_bounds__(256, 3) void gemm_qkv_kernel(const bf16* __restrict__ A,
                                                          const bf16* __restrict__ Wb,
                                                          GemmIO io) {
  __shared__ bf16 ldsA[128 * 64];
  __shared__ bf16 ldsB[128 * 64];
  const int t = threadIdx.x;
  const int m0 = blockIdx.x * 128;
  const int n0 = blockIdx.y * 128;
  const bf16* W = Wb + (size_t)blockIdx.z * 65536;
  const int w = t >> 6, l = t & 63, lm = l & 15, q = l >> 4;
  const int wr = (w >> 1) * 64, wc = (w & 1) * 64;

  f32x4 acc[4][4] = {};
#pragma unroll 1
  for (int it = 0; it < 4; ++it) {
    const int k0 = it * 64;
#pragma unroll
    for (int c = 0; c < 4; ++c) {
      int i = c * 256 + t;
      int r = i >> 3, c8 = (i & 7) ^ (r & 7);
      async16(A + (size_t)(m0 + r) * 256 + k0 + c8 * 8, &ldsA[i * 8]);
    }
#pragma unroll
    for (int c = 0; c < 4; ++c) {
      int i = c * 256 + t;
      int r = i >> 3, c8 = (i & 7) ^ (r & 7);
      async16(W + (size_t)(n0 + r) * 256 + k0 + c8 * 8, &ldsB[i * 8]);
    }
    __syncthreads();
#pragma unroll
    for (int ks = 0; ks < 2; ++ks) {
      bf16x8 af[4], bfr[4];
#pragma unroll
      for (int i = 0; i < 4; ++i) {
        int ra = wr + i * 16 + lm;
        af[i] = *(const bf16x8*)&ldsA[ra * 64 + ((((ks << 2) + q) ^ (ra & 7)) << 3)];
        int rb = wc + i * 16 + lm;
        bfr[i] = *(const bf16x8*)&ldsB[rb * 64 + ((((ks << 2) + q) ^ (rb & 7)) << 3)];
      }
#pragma unroll
      for (int i = 0; i < 4; ++i)
#pragma unroll
        for (int jj = 0; jj < 4; ++jj) acc[i][jj] = mfma16(af[i], bfr[jj], acc[i][jj]);
    }
    __syncthreads();
  }
  const float* bias = io.bias[blockIdx.z];
  if (blockIdx.z == 2) {
    // V: write fp8 V^T tile-major directly (fused transpose).
    u8* out = (u8*)io.out[2];
#pragma unroll
    for (int jj = 0; jj < 4; ++jj) {
      int col = n0 + wc + jj * 16 + lm;
      float bv = bias[col];
#pragma unroll
      for (int i = 0; i < 4; ++i) {
        int row = m0 + wr + i * 16 + q * 4;
#pragma unroll
        for (int r = 0; r < 4; ++r) {
          int rg = row + r;
          int bb = rg >> 12, s = rg & 4095;
          out[(((size_t)(bb * 64 + (s >> 6)) * 256 + col) << 6) + (s & 63)] =
              f2fp8(acc[i][jj][r] + bv);
        }
      }
    }
  } else {
    u8* out = (u8*)io.out[blockIdx.z];
#pragma unroll
    for (int jj = 0; jj < 4; ++jj) {
      int col = n0 + wc + jj * 16 + lm;
      int scol = (blockIdx.z == 1) ? permc(col) : col;  // K gets half-split cols
      float bv = bias[col];
#pragma unroll
      for (int i = 0; i < 4; ++i) {
        int row = m0 + wr + i * 16 + q * 4;
#pragma unroll
        for (int r = 0; r < 4; ++r)
          out[(size_t)(row + r) * 256 + scol] = f2fp8(acc[i][jj][r] + bv);
      }
    }
  }
}

// mu/lv GEMM (fp32 out) — same structure.
__global__ __launch_bounds__(256, 3) void gemm_f_kernel(const bf16* __restrict__ A,
                                                        const bf16* __restrict__ Wb, GemmIO io) {
  __shared__ bf16 ldsA[128 * 64];
  __shared__ bf16 ldsB[128 * 64];
  const int t = threadIdx.x;
  const int m0 = blockIdx.x * 128;
  const int n0 = blockIdx.y * 128;
  const bf16* W = Wb + (size_t)blockIdx.z * 65536;
  const int w = t >> 6, l = t & 63, lm = l & 15, q = l >> 4;
  const int wr = (w >> 1) * 64, wc = (w & 1) * 64;

  f32x4 acc[4][4] = {};
#pragma unroll 1
  for (int it = 0; it < 4; ++it) {
    const int k0 = it * 64;
#pragma unroll
    for (int c = 0; c < 4; ++c) {
      int i = c * 256 + t;
      int r = i >> 3, c8 = (i & 7) ^ (r & 7);
      async16(A + (size_t)(m0 + r) * 256 + k0 + c8 * 8, &ldsA[i * 8]);
    }
#pragma unroll
    for (int c = 0; c < 4; ++c) {
      int i = c * 256 + t;
      int r = i >> 3, c8 = (i & 7) ^ (r & 7);
      async16(W + (size_t)(n0 + r) * 256 + k0 + c8 * 8, &ldsB[i * 8]);
    }
    __syncthreads();
#pragma unroll
    for (int ks = 0; ks < 2; ++ks) {
      bf16x8 af[4], bfr[4];
#pragma unroll
      for (int i = 0; i < 4; ++i) {
        int ra = wr + i * 16 + lm;
        af[i] = *(const bf16x8*)&ldsA[ra * 64 + ((((ks << 2) + q) ^ (ra & 7)) << 3)];
        int rb = wc + i * 16 + lm;
        bfr[i] = *(const bf16x8*)&ldsB[rb * 64 + ((((ks << 2) + q) ^ (rb & 7)) << 3)];
      }
#pragma unroll
      for (int i = 0; i < 4; ++i)
#pragma unroll
        for (int jj = 0; jj < 4; ++jj) acc[i][jj] = mfma16(af[i], bfr[jj], acc[i][jj]);
    }
    __syncthreads();
  }
  const float* bias = io.bias[blockIdx.z];
  float* out = (float*)io.out[blockIdx.z];
#pragma unroll
  for (int jj = 0; jj < 4; ++jj) {
    int col = n0 + wc + jj * 16 + lm;
    float bv = bias[col];
#pragma unroll
    for (int i = 0; i < 4; ++i) {
      int row = m0 + wr + i * 16 + q * 4;
#pragma unroll
      for (int r = 0; r < 4; ++r)
        out[(size_t)(row + r) * 256 + col] = acc[i][jj][r] + bv;
    }
  }
}

// ---------------- flash attention v13: counted-vmcnt pipeline ----------------
// Grid 512 (2 blocks/CU), 384 threads = 6 waves. BM=32 Q rows/block, KV tile 64.
// Waves 0-1 = producers (ks=w): QK S^T strip mfma_mx(A=K_lds, B=Q_regs), k=256;
// softmax in regs; P(i) -> ldsP[i&1] (80B-padded rows, bank-even).
// Waves 2-5 = consumers (dpair=w-2): stage K(i+3) via global_load_lds into a
// 4-deep ring; prefetch V(i) global->regs (double reg set); PV(i-1) =
// mfma_mx(A=P_lds, B=V_regs), k=64, into o0/o1 (32q x 64d strips).
// Raw s_barrier per iter; NO vmcnt(0) in loop: the compiler's wait for the
// V-reg prefetch retires (in-order) exactly the K-staging loads that are due,
// giving every staged load ~2 iterations of latency slack.
// K LDS rows 256B permc over d, chunk^(row&7) swizzle: conflict-free b128.
__global__ __launch_bounds__(384, 3) void flash_kernel(const u8* __restrict__ Q,
                                                       const u8* __restrict__ K,
                                                       const u8* __restrict__ Vt,
                                                       bf16* __restrict__ O) {
  __shared__ __align__(16) u8 ldsK[4][16384];  // 64KB: 4-deep K ring
  __shared__ __align__(16) u8 ldsP[2][32 * 80];  // 5KB: P double buffer, 80B rows
  __shared__ float lb[32];

  const int id = blockIdx.x;
  const int xcd = id & 7;
  const int b = xcd >> 1;
  const int qt = (id >> 3) + ((xcd & 1) << 6);  // 0..127

  const u8* Qb = Q + (size_t)b * S_LEN * 256;
  const u8* Kb = K + (size_t)b * S_LEN * 256;
  const u8* Vb = Vt + (size_t)b * 64 * 16384;  // tile-major [64][256][64]
  bf16* Ob = O + (size_t)b * S_LEN * 256;

  const int t = threadIdx.x, w = t >> 6, lane = t & 63;
  const int m31 = lane & 31, kh = lane >> 5;
  const bool prod = (w < 2);
  const float CL2 = 0.09016844005556021f;  // log2(e)/sqrt(D)

  if (t < 32) lb[t] = 0.f;

  // ---- producer setup ----
  const int ks = w & 1;
  const int kn = ks * 32 + m31;
  const int kx = m31 & 7;
  i32x8 qf[4];
  if (prod) {
    const u8* qrow = Qb + (size_t)(qt * 32 + m31) * 256 + kh * 32;
#pragma unroll
    for (int b2 = 0; b2 < 4; ++b2) qf[b2] = *(const i32x8*)(qrow + b2 * 64);
  }
  float l_w = 0.f;

  // ---- consumer setup ----
  const int dpair = w - 2;               // 0..3
  const int vd0 = dpair * 64 + m31;      // V^T row (d)
  const int cl = dpair * 64 + lane;      // staging lane id 0..255
  f32x16 o0 = {}, o1 = {};
  i32x4 vA[4], vB[4];

  auto STAGE = [&](int m) {  // consumers: stage K tile m into ring slot m&3
    const u8* kg = Kb + (size_t)m * 16384;
    u8* kd = ldsK[m & 3];
#pragma unroll
    for (int jj = 0; jj < 4; ++jj) {
      int c = jj * 256 + cl;
      int kr = c >> 4, g = (c & 15) ^ (kr & 7);
      async16(kg + kr * 256 + g * 16, kd + c * 16);
    }
  };
  auto CONSV = [&](int m, i32x4* vr) {  // consumers: V tile m -> regs
    const u8* vt = Vb + (size_t)m * 16384 + (size_t)vd0 * 64 + kh * 32;
    vr[0] = *(const i32x4*)(vt);
    vr[1] = *(const i32x4*)(vt + 16);
    vr[2] = *(const i32x4*)(vt + 2048);
    vr[3] = *(const i32x4*)(vt + 2064);
  };
  auto PROD = [&](int i) {  // producers: QK tile i -> P(i)
    const u8* kb = &ldsK[i & 3][kn * 256 + kh * 128];
    f32x16 sA = {}, sB = {};
    {
      i32x4 c0 = *(const i32x4*)(kb + ((0 ^ kx) << 4));
      i32x4 c1 = *(const i32x4*)(kb + ((1 ^ kx) << 4));
      sA = mfma_mx(cat8(c0, c1), qf[0], sA);
      i32x4 c2 = *(const i32x4*)(kb + ((2 ^ kx) << 4));
      i32x4 c3 = *(const i32x4*)(kb + ((3 ^ kx) << 4));
      sB = mfma_mx(cat8(c2, c3), qf[1], sB);
      i32x4 c4 = *(const i32x4*)(kb + ((4 ^ kx) << 4));
      i32x4 c5 = *(const i32x4*)(kb + ((5 ^ kx) << 4));
      sA = mfma_mx(cat8(c4, c5), qf[2], sA);
      i32x4 c6 = *(const i32x4*)(kb + ((6 ^ kx) << 4));
      i32x4 c7 = *(const i32x4*)(kb + ((7 ^ kx) << 4));
      sB = mfma_mx(cat8(c6, c7), qf[3], sB);
    }
    float p[16];
    float l0 = 0.f, l1 = 0.f, l2 = 0.f, l3 = 0.f;
#pragma unroll
    for (int r = 0; r < 16; ++r) {
      p[r] = __builtin_amdgcn_exp2f((sA[r] + sB[r]) * CL2);
      if ((r & 3) == 0) l0 += p[r];
      else if ((r & 3) == 1) l1 += p[r];
      else if ((r & 3) == 2) l2 += p[r];
      else l3 += p[r];
    }
    l_w += (l0 + l1) + (l2 + l3);
    u8* pst = &ldsP[i & 1][m31 * 80 + ks * 32 + 4 * kh];
#pragma unroll
    for (int g2 = 0; g2 < 4; ++g2) {
      int pk = __builtin_amdgcn_cvt_pk_fp8_f32(p[4 * g2], p[4 * g2 + 1], 0, false);
      pk = __builtin_amdgcn_cvt_pk_fp8_f32(p[4 * g2 + 2], p[4 * g2 + 3], pk, true);
      *(u32*)(pst + 8 * g2) = (u32)pk;  // kv = ks*32 + 8*g2 + 4*kh + {0..3}
    }
  };
  auto PV = [&](int i, const i32x4* vr) {  // consumers: O += P(i) * V(i)
    const u8* pr = &ldsP[i & 1][m31 * 80 + kh * 32];
    i32x4 plo = *(const i32x4*)(pr);
    i32x4 phi = *(const i32x4*)(pr + 16);
    i32x8 pa = cat8(plo, phi);
    o0 = mfma_mx(pa, cat8(vr[0], vr[1]), o0);
    o1 = mfma_mx(pa, cat8(vr[2], vr[3]), o1);
  };

  // ---- prologue: stage K(0..2) cooperatively (all 6 waves, 8 chunks each) ----
#pragma unroll
  for (int rep = 0; rep < 8; ++rep) {
    int c = rep * 384 + t;          // 0..3071
    int tile = c >> 10, cc = c & 1023;
    int kr = cc >> 4, g = (cc & 15) ^ (kr & 7);
    async16(Kb + tile * 16384 + kr * 256 + g * 16, &ldsK[tile][cc * 16]);
  }
  asm volatile("s_waitcnt vmcnt(0) lgkmcnt(0)" ::: "memory");
  __builtin_amdgcn_s_barrier();
  asm volatile("" ::: "memory");

  // ---- i = 0 (peel) ----
  if (prod) {
    PROD(0);
    asm volatile("s_waitcnt lgkmcnt(0)" ::: "memory");
  } else {
    CONSV(0, vA);
    STAGE(3);
  }
  __builtin_amdgcn_s_barrier();
  asm volatile("" ::: "memory");

  // ---- main loop, pairs (odd, even) ----
#pragma unroll 1
  for (int ii = 1; ii < 63; ii += 2) {
    if (prod) {
      PROD(ii);
      asm volatile("s_waitcnt lgkmcnt(0)" ::: "memory");
    } else {
      CONSV(ii, vB);
      if (ii + 3 < 64) STAGE(ii + 3);
      PV(ii - 1, vA);
    }
    __builtin_amdgcn_s_barrier();
    asm volatile("" ::: "memory");
    if (prod) {
      PROD(ii + 1);
      asm volatile("s_waitcnt lgkmcnt(0)" ::: "memory");
    } else {
      CONSV(ii + 1, vA);
      if (ii + 4 < 64) STAGE(ii + 4);
      PV(ii, vB);
    }
    __builtin_amdgcn_s_barrier();
    asm volatile("" ::: "memory");
  }

  // ---- i = 63 (peel) ----
  if (prod) {
    PROD(63);
    asm volatile("s_waitcnt lgkmcnt(0)" ::: "memory");
  } else {
    CONSV(63, vB);
    PV(62, vA);
  }
  __builtin_amdgcn_s_barrier();
  asm volatile("" ::: "memory");

  // ---- epilogue: consumers finish PV(63); producers reduce l ----
  if (prod) {
    l_w += __shfl_xor(l_w, 32, 64);
    if (kh == 0) atomicAdd(&lb[m31], l_w);
  } else {
    PV(63, vB);
  }
  __syncthreads();

  if (!prod) {
    bf16* ob = Ob + (size_t)(qt * 32) * 256 + dpair * 64;
#pragma unroll
    for (int reg = 0; reg < 16; ++reg) {
      const int row = (reg & 3) + 8 * (reg >> 2) + 4 * kh;
      float li = lb[row];
      ob[(size_t)row * 256 + m31] = (bf16)(o0[reg] / li);
      ob[(size_t)row * 256 + 32 + m31] = (bf16)(o1[reg] / li);
    }
  }
}

// ---------------- gate: mean over S then dot Wg + sigmoid ----------------
__global__ __launch_bounds__(256) void gate_partial(const bf16* __restrict__ h,
                                                    float* __restrict__ part) {
  int bb = blockIdx.y;
  const bf16* hb = h + (size_t)bb * S_LEN * 256 + (size_t)blockIdx.x * 64 * 256;
  int t = threadIdx.x;
  float acc = 0.f;
#pragma unroll 4
  for (int s = 0; s < 64; ++s) acc += (float)hb[s * 256 + t];
  part[((size_t)bb * 64 + blockIdx.x) * 256 + t] = acc;
}

__global__ __launch_bounds__(256) void gate_final(const float* __restrict__ part,
                                                  const float* __restrict__ Wg,
                                                  const float* __restrict__ bg,
                                                  float* __restrict__ pg) {
  int bb = blockIdx.x, t = threadIdx.x;
  const float* p = part + (size_t)bb * 64 * 256;
  float acc = 0.f;
#pragma unroll 4
  for (int c = 0; c < 64; ++c) acc += p[c * 256 + t];
  acc *= Wg[t] * (1.0f / 4096.0f);
  __shared__ float red[256];
  red[t] = acc;
  __syncthreads();
  if (t < 64) {
    float a = red[t] + red[t + 64] + red[t + 128] + red[t + 192];
#pragma unroll
    for (int d = 1; d < 64; d <<= 1) a += __shfl_xor(a, d, 64);
    if (t == 0) pg[bb] = 1.0f / (1.0f + __expf(-(a + bg[0])));
  }
}

// ---------------- fused reparam + ELU + residual + LayerNorm ----------------
__global__ __launch_bounds__(256) void epilogue_kernel(const float* __restrict__ x,
                                                       const float* __restrict__ eps,
                                                       const float* __restrict__ mu,
                                                       const float* __restrict__ lv,
                                                       const float* __restrict__ gamma,
                                                       const float* __restrict__ beta,
                                                       float* __restrict__ out) {
  size_t base = (size_t)blockIdx.x * 1024 + (threadIdx.x >> 6) * 256;
  int l = threadIdx.x & 63;
  f32x4 xv = ((const f32x4*)(x + base))[l];
  f32x4 ev = ((const f32x4*)(eps + base))[l];
  f32x4 mv = ((const f32x4*)(mu + base))[l];
  f32x4 vv = ((const f32x4*)(lv + base))[l];
  f32x4 y;
  float s = 0.f, s2 = 0.f;
#pragma unroll
  for (int c = 0; c < 4; ++c) {
    float z = mv[c] + ev[c] * __expf(0.5f * vv[c]);
    z = z > 0.f ? z : (__expf(z) - 1.f);
    float yy = xv[c] + z;
    y[c] = yy;
    s += yy;
    s2 += yy * yy;
  }
#pragma unroll
  for (int d = 1; d < 64; d <<= 1) {
    s += __shfl_xor(s, d, 64);
    s2 += __shfl_xor(s2, d, 64);
  }
  float mean = s * (1.f / 256.f);
  float var = s2 * (1.f / 256.f) - mean * mean;
  float rstd = rsqrtf(var + 1e-5f);
  f32x4 gv = ((const f32x4*)gamma)[l];
  f32x4 bv = ((const f32x4*)beta)[l];
  f32x4 o;
#pragma unroll
  for (int c = 0; c < 4; ++c) o[c] = (y[c] - mean) * rstd * gv[c] + bv[c];
  ((f32x4*)(out + base))[l] = o;
}

// ---------------- launch ----------------
extern "C" void kernel_launch(void* const* d_in, const int* in_sizes, int n_in, void* d_out,
                              int out_size, void* d_ws, size_t ws_size, hipStream_t stream) {
  const float* x = (const float*)d_in[0];
  const float* eps = (const float*)d_in[1];
  const float* Wg = (const float*)d_in[18];
  const float* bg = (const float*)d_in[19];
  const float* gamma = (const float*)d_in[20];
  const float* beta = (const float*)d_in[21];

  char* ws = (char*)d_ws;
  bf16* x16 = (bf16*)(ws);                  // 8 MB
  bf16* h16 = (bf16*)(ws + 8388608);        // 8 MB
  u8* q8 = (u8*)(ws + 25165824);            // 4 MB
  u8* k8 = (u8*)(ws + 29360128);            // 4 MB
  u8* vt8 = (u8*)(ws + 33554432);           // 4 MB (V^T fp8 tile-major)
  bf16* w16 = (bf16*)(ws + 37748736);       // 1 MB (8 x 256x256 bf16)
  float* gpart = (float*)(ws + 38797312);   // 256 KB

  float* out = (float*)d_out;
  float* mu = out + 4194304;
  float* lv = out + 8388608;
  float* pg = out + 12582912;

  WPtrs wp;
  for (int i = 0; i < 8; ++i) wp.p[i] = (const float*)d_in[2 + i];
  cast_all_kernel<<<4608, 256, 0, stream>>>((const f32x4*)x, wp, (ushort4*)x16, (ushort4*)w16);

  GemmIO io1;
  io1.bias[0] = (const float*)d_in[10];
  io1.bias[1] = (const float*)d_in[11];
  io1.bias[2] = (const float*)d_in[12];
  io1.out[0] = q8; io1.out[1] = k8; io1.out[2] = vt8;
  gemm_qkv_kernel<<<dim3(128, 2, 3), 256, 0, stream>>>(x16, w16, io1);
  flash_kernel<<<512, 384, 0, stream>>>(q8, k8, vt8, h16);

  GemmIO io2;
  io2.bias[0] = (const float*)d_in[13];
  io2.bias[1] = (const float*)d_in[14];
  io2.bias[2] = (const float*)d_in[15];
  io2.out[0] = q8; io2.out[1] = k8; io2.out[2] = vt8;
  gemm_qkv_kernel<<<dim3(128, 2, 3), 256, 0, stream>>>(h16, w16 + 3 * 65536, io2);
  flash_kernel<<<512, 384, 0, stream>>>(q8, k8, vt8, h16);

  GemmIO io3;
  io3.bias[0] = (const float*)d_in[16];
  io3.bias[1] = (const float*)d_in[17];
  io3.bias[2] = nullptr;
  io3.out[0] = mu; io3.out[1] = lv; io3.out[2] = nullptr;
  gemm_f_kernel<<<dim3(128, 2, 2), 256, 0, stream>>>(h16, w16 + 6 * 65536, io3);

  gate_partial<<<dim3(64, 4), 256, 0, stream>>>(h16, gpart);
  gate_final<<<4, 256, 0, stream>>>(gpart, Wg, bg, pg);
  epilogue_kernel<<<4096, 256, 0, stream>>>(x, eps, mu, lv, gamma, beta, out);
}